// Round 16
// baseline (170.344 us; speedup 1.0000x reference)
//
#include <hip/hip_runtime.h>
#include <hip/hip_bf16.h>

// HardgroupAttention: B=4, N=1024, C=384, heads=12, hd=32, GP=20.
// conv3 -> wgp_fuse + group argmax (fp64 exact, vectorized) -> gemm_qkv
// (128x64 dbuf, Q pre-scaled SCALE*log2e) -> score5 (ONE QK^T MFMA sweep:
// rowsum->rinv AND E=keep*exp2 bf16 via kt-pair bounce transpose, 16B/lane
// NT stores) -> colv (colsum=sum E*rinv -> ci; V'=V*ci bf16 hi/lo transp)
// -> pv5 (pure GEMM E @ V', epilogue *rinv) -> gemm_proj (64x64 dbuf).

#define B_    4
#define N_    1024
#define C_    384
#define H3_   1152
#define NH_   12
#define HD_   32
#define GP_   20
#define BH_   48
#define QSCALE 0.2550029971791444f   // (hd^-0.5) * log2(e)

typedef __attribute__((ext_vector_type(8))) short bf16x8;
typedef __attribute__((ext_vector_type(4))) float f32x4;
typedef __attribute__((ext_vector_type(4))) unsigned u32x4;

static __device__ __forceinline__ unsigned short f2bf(float x) {
  union { float f; unsigned u; } v; v.f = x;
  unsigned r = v.u + 0x7fff + ((v.u >> 16) & 1);   // RNE
  return (unsigned short)(r >> 16);
}
static __device__ __forceinline__ float bf2f(unsigned short h) {
  union { unsigned u; float f; } v; v.u = ((unsigned)h) << 16;
  return v.f;
}

// ---------------- conv3: split x / Wqkv / Wproj into bf16 hi/lo -------------
__global__ __launch_bounds__(256) void conv3(const float* __restrict__ x,
                                             const float* __restrict__ wq,
                                             const float* __restrict__ wp,
                                             unsigned short* __restrict__ xh,
                                             unsigned short* __restrict__ xl,
                                             unsigned short* __restrict__ wqh,
                                             unsigned short* __restrict__ wql,
                                             unsigned short* __restrict__ wph,
                                             unsigned short* __restrict__ wpl) {
  const int NX = (4096 * C_) / 4, NQ = (H3_ * C_) / 4, NP = (C_ * C_) / 4;
  int idx = blockIdx.x * 256 + threadIdx.x;
  const float* src; unsigned short *dh, *dl; int o;
  if (idx < NX)            { src = x;  dh = xh;  dl = xl;  o = idx; }
  else if (idx < NX + NQ)  { src = wq; dh = wqh; dl = wql; o = idx - NX; }
  else if (idx < NX + NQ + NP) { src = wp; dh = wph; dl = wpl; o = idx - NX - NQ; }
  else return;
  float4 v = *(const float4*)(src + (size_t)o * 4);
  float a[4] = {v.x, v.y, v.z, v.w};
  unsigned short h[4], lo[4];
  #pragma unroll
  for (int i = 0; i < 4; ++i) { h[i] = f2bf(a[i]); lo[i] = f2bf(a[i] - bf2f(h[i])); }
  uint2 ph = {(unsigned)h[0]  | ((unsigned)h[1]  << 16),
              (unsigned)h[2]  | ((unsigned)h[3]  << 16)};
  uint2 pl = {(unsigned)lo[0] | ((unsigned)lo[1] << 16),
              (unsigned)lo[2] | ((unsigned)lo[3] << 16)};
  *(uint2*)(dh + (size_t)o * 4) = ph;
  *(uint2*)(dl + (size_t)o * 4) = pl;
}

// ---------------- M[g][c] = sum_j Wgp[g][j] * Wqkv[j][c]  (fp64) ------------
__global__ __launch_bounds__(256) void wgp_fuse(const float* __restrict__ Wqkv,
                                                const float* __restrict__ Wgp,
                                                double* __restrict__ M) {
  int idx = blockIdx.x * 256 + threadIdx.x;
  if (idx >= GP_ * C_) return;
  int g = idx / C_, c = idx % C_;
  double acc = 0.0;
  for (int j = 0; j < C_; ++j)
    acc += (double)Wgp[g * C_ + j] * (double)Wqkv[(size_t)j * C_ + c];
  M[idx] = acc;
}

// ---------------- group argmax from exact x (fp64, vectorized loads) --------
__global__ __launch_bounds__(320) void group_assign2(const float* __restrict__ x,
                                                     const double* __restrict__ M,
                                                     int* __restrict__ group) {
  __shared__ double sc[16][GP_];
  int tid = threadIdx.x;
  int r = tid / GP_, g = tid % GP_;
  int n = blockIdx.x * 16 + r;
  const float* row = x + (size_t)n * C_;
  const double* w = M + (size_t)g * C_;
  double acc = 0.0;
  #pragma unroll 4
  for (int c = 0; c < C_; c += 4) {
    float4 xv = *(const float4*)(row + c);
    double2 w0 = *(const double2*)(w + c);
    double2 w1 = *(const double2*)(w + c + 2);
    acc += (double)xv.x * w0.x + (double)xv.y * w0.y +
           (double)xv.z * w1.x + (double)xv.w * w1.y;
  }
  sc[r][g] = acc;
  __syncthreads();
  if (g == 0) {
    int best = 0; double bv = sc[r][0];
    #pragma unroll
    for (int j = 1; j < GP_; ++j)
      if (sc[r][j] > bv) { bv = sc[r][j]; best = j; }
    group[n] = best;
  }
}

// ---------------- gemm_qkv: 128x64 tile, dbuf LDS, async-stage split --------
__global__ __launch_bounds__(256) void gemm_qkv(
    const unsigned short* __restrict__ Ah_g, const unsigned short* __restrict__ Al_g,
    const unsigned short* __restrict__ Bh_g, const unsigned short* __restrict__ Bl_g,
    unsigned short* __restrict__ Qh, unsigned short* __restrict__ Ql,
    unsigned short* __restrict__ Kh, unsigned short* __restrict__ Kl,
    float* __restrict__ Vf) {
  __shared__ __align__(16) unsigned short sAh[2][128 * 32];
  __shared__ __align__(16) unsigned short sAl[2][128 * 32];
  __shared__ __align__(16) unsigned short sBh[2][64 * 32];
  __shared__ __align__(16) unsigned short sBl[2][64 * 32];
  int tid = threadIdx.x;
  int l = tid & 63, w = tid >> 6;
  int lanelo = l & 15, g16 = l >> 4;
  int wr = w >> 1, wc = w & 1;
  int flat = blockIdx.x;
  int swz = (flat & 7) * 72 + (flat >> 3);   // 576 = 8*72, bijective
  int bm = swz / 18, bn = swz % 18;

  int ra = tid >> 2, c4 = tid & 3;
  const unsigned short* gAh0 = Ah_g + (size_t)(bm * 128 + ra) * C_ + c4 * 8;
  const unsigned short* gAl0 = Al_g + (size_t)(bm * 128 + ra) * C_ + c4 * 8;
  const unsigned short* gBh0 = Bh_g + (size_t)(bn * 64 + ra) * C_ + c4 * 8;
  const unsigned short* gBl0 = Bl_g + (size_t)(bn * 64 + ra) * C_ + c4 * 8;
  int dsa = ra * 32 + ((c4 ^ (ra & 3)) * 8);

  uint4 r0 = *(const uint4*)(gAh0);
  uint4 r1 = *(const uint4*)(gAh0 + (size_t)64 * C_);
  uint4 r2 = *(const uint4*)(gAl0);
  uint4 r3 = *(const uint4*)(gAl0 + (size_t)64 * C_);
  uint4 r4 = *(const uint4*)(gBh0);
  uint4 r5 = *(const uint4*)(gBl0);

  f32x4 acc[4][2];
  #pragma unroll
  for (int i = 0; i < 4; ++i)
    #pragma unroll
    for (int j = 0; j < 2; ++j) acc[i][j] = (f32x4){0.f, 0.f, 0.f, 0.f};

  int p = 0;
  for (int kk = 0; kk < 12; ++kk) {
    *(uint4*)(&sAh[p][dsa])           = r0;
    *(uint4*)(&sAh[p][dsa + 64 * 32]) = r1;
    *(uint4*)(&sAl[p][dsa])           = r2;
    *(uint4*)(&sAl[p][dsa + 64 * 32]) = r3;
    *(uint4*)(&sBh[p][dsa])           = r4;
    *(uint4*)(&sBl[p][dsa])           = r5;
    __syncthreads();
    if (kk < 11) {
      int ko = (kk + 1) * 32;
      r0 = *(const uint4*)(gAh0 + ko);
      r1 = *(const uint4*)(gAh0 + (size_t)64 * C_ + ko);
      r2 = *(const uint4*)(gAl0 + ko);
      r3 = *(const uint4*)(gAl0 + (size_t)64 * C_ + ko);
      r4 = *(const uint4*)(gBh0 + ko);
      r5 = *(const uint4*)(gBl0 + ko);
    }
    bf16x8 ah[4], al[4], bh8[2], bl8[2];
    #pragma unroll
    for (int i = 0; i < 4; ++i) {
      int row = wr * 64 + i * 16 + lanelo;
      int off = row * 32 + ((g16 ^ (row & 3)) * 8);
      ah[i] = *(const bf16x8*)(&sAh[p][off]);
      al[i] = *(const bf16x8*)(&sAl[p][off]);
    }
    #pragma unroll
    for (int j = 0; j < 2; ++j) {
      int row = wc * 32 + j * 16 + lanelo;
      int off = row * 32 + ((g16 ^ (row & 3)) * 8);
      bh8[j] = *(const bf16x8*)(&sBh[p][off]);
      bl8[j] = *(const bf16x8*)(&sBl[p][off]);
    }
    #pragma unroll
    for (int i = 0; i < 4; ++i)
      #pragma unroll
      for (int j = 0; j < 2; ++j) {
        acc[i][j] = __builtin_amdgcn_mfma_f32_16x16x32_bf16(ah[i], bh8[j], acc[i][j], 0, 0, 0);
        acc[i][j] = __builtin_amdgcn_mfma_f32_16x16x32_bf16(ah[i], bl8[j], acc[i][j], 0, 0, 0);
        acc[i][j] = __builtin_amdgcn_mfma_f32_16x16x32_bf16(al[i], bh8[j], acc[i][j], 0, 0, 0);
      }
    p ^= 1;
  }

  int region = bn / 6;   // 0=Q 1=K 2=V (block-uniform; 6 bn-tiles each)
  #pragma unroll
  for (int i = 0; i < 4; ++i) {
    int mm0 = bm * 128 + wr * 64 + i * 16 + g16 * 4;
    #pragma unroll
    for (int j = 0; j < 2; ++j) {
      int c = bn * 64 + wc * 32 + j * 16 + lanelo;
      int cc = c - region * 384;   // 0..383
      #pragma unroll
      for (int t = 0; t < 4; ++t) {
        int mm = mm0 + t;
        int b = mm >> 10, n = mm & 1023;
        float v = acc[i][j][t];
        if (region == 0) {
          v *= QSCALE;                 // fold log2e: attn uses exp2
          unsigned short h = f2bf(v), lo = f2bf(v - bf2f(h));
          size_t idx = ((size_t)(b * NH_ + (cc >> 5)) * N_ + n) * HD_ + (cc & 31);
          Qh[idx] = h; Ql[idx] = lo;
        } else if (region == 1) {
          unsigned short h = f2bf(v), lo = f2bf(v - bf2f(h));
          size_t idx = ((size_t)(b * NH_ + (cc >> 5)) * N_ + n) * HD_ + (cc & 31);
          Kh[idx] = h; Kl[idx] = lo;
        } else {
          Vf[(size_t)mm * C_ + cc] = v;
        }
      }
    }
  }
}

// ---------------- gemm_proj: 64x64 tile, dbuf LDS, async-stage split --------
__global__ __launch_bounds__(256) void gemm_proj(
    const unsigned short* __restrict__ Ah_g, const unsigned short* __restrict__ Al_g,
    const unsigned short* __restrict__ Bh_g, const unsigned short* __restrict__ Bl_g,
    float* __restrict__ Cm) {
  __shared__ __align__(16) unsigned short sAh[2][64 * 32];
  __shared__ __align__(16) unsigned short sAl[2][64 * 32];
  __shared__ __align__(16) unsigned short sBh[2][64 * 32];
  __shared__ __align__(16) unsigned short sBl[2][64 * 32];
  int tid = threadIdx.x;
  int l = tid & 63, w = tid >> 6;
  int lanelo = l & 15, g16 = l >> 4;
  int wr = w >> 1, wc = w & 1;
  int flat = blockIdx.x;
  int swz = (flat & 7) * 48 + (flat >> 3);   // 384 = 8*48, bijective
  int bm = swz / 6, bn = swz % 6;

  int ra = tid >> 2, c4 = tid & 3;
  const unsigned short* gAh0 = Ah_g + (size_t)(bm * 64 + ra) * C_ + c4 * 8;
  const unsigned short* gAl0 = Al_g + (size_t)(bm * 64 + ra) * C_ + c4 * 8;
  const unsigned short* gBh0 = Bh_g + (size_t)(bn * 64 + ra) * C_ + c4 * 8;
  const unsigned short* gBl0 = Bl_g + (size_t)(bn * 64 + ra) * C_ + c4 * 8;
  int dsa = ra * 32 + ((c4 ^ (ra & 3)) * 8);

  uint4 r0 = *(const uint4*)(gAh0);
  uint4 r1 = *(const uint4*)(gAl0);
  uint4 r2 = *(const uint4*)(gBh0);
  uint4 r3 = *(const uint4*)(gBl0);

  f32x4 acc[2][2];
  #pragma unroll
  for (int i = 0; i < 2; ++i)
    #pragma unroll
    for (int j = 0; j < 2; ++j) acc[i][j] = (f32x4){0.f, 0.f, 0.f, 0.f};

  int p = 0;
  for (int kk = 0; kk < 12; ++kk) {
    *(uint4*)(&sAh[p][dsa]) = r0;
    *(uint4*)(&sAl[p][dsa]) = r1;
    *(uint4*)(&sBh[p][dsa]) = r2;
    *(uint4*)(&sBl[p][dsa]) = r3;
    __syncthreads();
    if (kk < 11) {
      int ko = (kk + 1) * 32;
      r0 = *(const uint4*)(gAh0 + ko);
      r1 = *(const uint4*)(gAl0 + ko);
      r2 = *(const uint4*)(gBh0 + ko);
      r3 = *(const uint4*)(gBl0 + ko);
    }
    bf16x8 ah[2], al[2], bh8[2], bl8[2];
    #pragma unroll
    for (int i = 0; i < 2; ++i) {
      int row = wr * 32 + i * 16 + lanelo;
      int off = row * 32 + ((g16 ^ (row & 3)) * 8);
      ah[i] = *(const bf16x8*)(&sAh[p][off]);
      al[i] = *(const bf16x8*)(&sAl[p][off]);
    }
    #pragma unroll
    for (int j = 0; j < 2; ++j) {
      int row = wc * 32 + j * 16 + lanelo;
      int off = row * 32 + ((g16 ^ (row & 3)) * 8);
      bh8[j] = *(const bf16x8*)(&sBh[p][off]);
      bl8[j] = *(const bf16x8*)(&sBl[p][off]);
    }
    #pragma unroll
    for (int i = 0; i < 2; ++i)
      #pragma unroll
      for (int j = 0; j < 2; ++j) {
        acc[i][j] = __builtin_amdgcn_mfma_f32_16x16x32_bf16(ah[i], bh8[j], acc[i][j], 0, 0, 0);
        acc[i][j] = __builtin_amdgcn_mfma_f32_16x16x32_bf16(ah[i], bl8[j], acc[i][j], 0, 0, 0);
        acc[i][j] = __builtin_amdgcn_mfma_f32_16x16x32_bf16(al[i], bh8[j], acc[i][j], 0, 0, 0);
      }
    p ^= 1;
  }
  #pragma unroll
  for (int i = 0; i < 2; ++i) {
    int mm = bm * 64 + wr * 32 + i * 16 + g16 * 4;
    #pragma unroll
    for (int j = 0; j < 2; ++j) {
      int c = bn * 64 + wc * 32 + j * 16 + lanelo;
      #pragma unroll
      for (int t = 0; t < 4; ++t)
        Cm[(size_t)(mm + t) * C_ + c] = acc[i][j][t];
    }
  }
}

// ---------------- score5: ONE QK^T sweep -> rinv + E (bf16, 16B NT stores) --
// grid (16 qblk, 48 bh) XCD-swz, 768 blocks; 4 waves x 16 q-rows.
// E layout: [bh][kt=m/16][n][16] bf16. kt-pair bounce -> 16B/lane NT stores.
__global__ __launch_bounds__(256) void score5(const unsigned short* __restrict__ Qh,
                                              const unsigned short* __restrict__ Ql,
                                              const unsigned short* __restrict__ Kh,
                                              const unsigned short* __restrict__ Kl,
                                              const int* __restrict__ group,
                                              float* __restrict__ rinv,
                                              unsigned short* __restrict__ E) {
  __shared__ __align__(16) unsigned short kbufh[4096];   // [128kv][32d] swz
  __shared__ __align__(16) unsigned short kbufl[4096];
  __shared__ __align__(16) float bounce[4][512];         // per-wave 2x(16x16), swz
  __shared__ int g_s[1024];
  int tid = threadIdx.x;
  int l = tid & 63, w = tid >> 6;
  int lanelo = l & 15, g16 = l >> 4;
  int flat = blockIdx.y * 16 + blockIdx.x;
  int nf = (flat & 7) * 96 + (flat >> 3);
  int bh = nf >> 4, blk = nf & 15;
  int b = bh / NH_;
  bool samehead = ((bh % NH_) < NH_ / 2);
  int q0 = blk * 64 + w * 16;
  size_t bhb = (size_t)bh * (N_ * HD_);

  *(int4*)&g_s[tid * 4] = *(const int4*)(group + b * N_ + tid * 4);
  bf16x8 aQh = *(const bf16x8*)(Qh + bhb + (size_t)(q0 + lanelo) * HD_ + g16 * 8);
  bf16x8 aQl = *(const bf16x8*)(Ql + bhb + (size_t)(q0 + lanelo) * HD_ + g16 * 8);
  __syncthreads();
  int gq[4];
  #pragma unroll
  for (int t = 0; t < 4; ++t) gq[t] = g_s[q0 + g16 * 4 + t];

  float s4[4] = {0.f, 0.f, 0.f, 0.f};
  size_t Eb = (size_t)bh * 64 * 1024 * 16;

  // write-phase lane map (constant per thread)
  int wtile = l >> 5;              // 0/1: which kt of the pair
  int wrow  = (l >> 1) & 15;       // q-row within tile
  int whalf = l & 1;               // which 8-col half
  int wb    = wtile * 256 + wrow * 16;
  int wp0   = (((2 * whalf)     ^ (wrow & 3) ^ (wrow >> 2)) << 2);
  int wp1   = (((2 * whalf + 1) ^ (wrow & 3) ^ (wrow >> 2)) << 2);

  for (int ch = 0; ch < 8; ++ch) {
    __syncthreads();
    #pragma unroll
    for (int t2 = 0; t2 < 2; ++t2) {
      int f2 = t2 * 256 + tid;
      int row = f2 >> 2, c4 = f2 & 3;
      uint4 vh = *(const uint4*)(Kh + bhb + (size_t)(ch * 128 + row) * HD_ + c4 * 8);
      uint4 vl = *(const uint4*)(Kl + bhb + (size_t)(ch * 128 + row) * HD_ + c4 * 8);
      int phys = row * 64 + ((c4 ^ (row & 3)) << 4);
      *(uint4*)((char*)kbufh + phys) = vh;
      *(uint4*)((char*)kbufl + phys) = vl;
    }
    __syncthreads();
    #pragma unroll
    for (int kt2 = 0; kt2 < 8; kt2 += 2) {
      #pragma unroll
      for (int sub = 0; sub < 2; ++sub) {
        int kt2s = kt2 + sub;
        int kt = ch * 8 + kt2s;
        int kvl = kt2s * 16 + lanelo;
        int phys = kvl * 64 + ((g16 ^ (kvl & 3)) << 4);
        bf16x8 bh8 = *(const bf16x8*)((char*)kbufh + phys);
        bf16x8 bl8 = *(const bf16x8*)((char*)kbufl + phys);
        f32x4 acc = {0.f, 0.f, 0.f, 0.f};
        acc = __builtin_amdgcn_mfma_f32_16x16x32_bf16(aQh, bh8, acc, 0, 0, 0);
        acc = __builtin_amdgcn_mfma_f32_16x16x32_bf16(aQh, bl8, acc, 0, 0, 0);
        acc = __builtin_amdgcn_mfma_f32_16x16x32_bf16(aQl, bh8, acc, 0, 0, 0);
        int gcol = g_s[kt * 16 + lanelo];
        #pragma unroll
        for (int t = 0; t < 4; ++t) {
          float e = exp2f(acc[t]);
          s4[t] += e;                               // rowsum over ALL m
          int r = g16 * 4 + t;
          bool keep = ((gcol == gq[t]) == samehead);
          float me = keep ? e : 0.f;
          int pc = (lanelo >> 2) ^ (r & 3) ^ (r >> 2);
          bounce[w][sub * 256 + r * 16 + pc * 4 + (lanelo & 3)] = me;
        }
      }
      // 16B/lane coalesced NT store: lane covers (tile, row, 8 cols)
      float4 f0 = *(float4*)&bounce[w][wb + wp0];
      float4 f1 = *(float4*)&bounce[w][wb + wp1];
      u32x4 st;
      st.x = ((unsigned)f2bf(f0.y) << 16) | f2bf(f0.x);
      st.y = ((unsigned)f2bf(f0.w) << 16) | f2bf(f0.z);
      st.z = ((unsigned)f2bf(f1.y) << 16) | f2bf(f1.x);
      st.w = ((unsigned)f2bf(f1.w) << 16) | f2bf(f1.z);
      int ktw = ch * 8 + kt2 + wtile;
      __builtin_nontemporal_store(st,
          (u32x4*)(E + Eb + ((size_t)ktw * 1024 + q0 + wrow) * 16 + whalf * 8));
    }
  }
  #pragma unroll
  for (int t = 0; t < 4; ++t) {
    #pragma unroll
    for (int off = 1; off < 16; off <<= 1) s4[t] += __shfl_xor(s4[t], off);
  }
  if (lanelo == 0) {
    #pragma unroll
    for (int t = 0; t < 4; ++t)
      rinv[(size_t)bh * N_ + q0 + g16 * 4 + t] = 1.0f / s4[t];
  }
}

// ---------------- colv: colsum = sum_n E*rinv -> ci; V' = V*ci (transposed) -
__global__ __launch_bounds__(256) void colv(const unsigned short* __restrict__ E,
                                            const float* __restrict__ rinv,
                                            const float* __restrict__ Vf,
                                            unsigned short* __restrict__ Vth,
                                            unsigned short* __restrict__ Vtl) {
  __shared__ float wsum[4][16];
  __shared__ float colinv_s[16];
  __shared__ unsigned short vh_s[32][16];
  __shared__ unsigned short vl_s[32][16];
  int tid = threadIdx.x;
  int l = tid & 63, w = tid >> 6;
  int flat = blockIdx.y * 64 + blockIdx.x;
  int nf = (flat & 7) * 384 + (flat >> 3);
  int bh = nf >> 6, mt = nf & 63;
  int b = bh / NH_, hd = bh % NH_;
  const unsigned short* Eb = E + ((size_t)(bh * 64 + mt)) * 1024 * 16;
  const float* rv = rinv + (size_t)bh * N_;

  float s[16] = {};
  #pragma unroll
  for (int p = 0; p < 4; ++p) {
    int n = p * 256 + tid;
    uint4 a = *(const uint4*)(Eb + (size_t)n * 16);
    uint4 c = *(const uint4*)(Eb + (size_t)n * 16 + 8);
    float rn = rv[n];
    unsigned ua[8] = {a.x, a.y, a.z, a.w, c.x, c.y, c.z, c.w};
    #pragma unroll
    for (int i = 0; i < 8; ++i) {
      s[2 * i]     += bf2f((unsigned short)(ua[i] & 0xffff)) * rn;
      s[2 * i + 1] += bf2f((unsigned short)(ua[i] >> 16)) * rn;
    }
  }
  #pragma unroll
  for (int i = 0; i < 16; ++i) {
    #pragma unroll
    for (int off = 1; off < 64; off <<= 1) s[i] += __shfl_xor(s[i], off);
  }
  if (l == 0) {
    #pragma unroll
    for (int i = 0; i < 16; ++i) wsum[w][i] = s[i];
  }
  __syncthreads();
  if (tid < 16)
    colinv_s[tid] = 1.0f / (wsum[0][tid] + wsum[1][tid] + wsum[2][tid] +
                            wsum[3][tid] + 1e-8f);
  __syncthreads();
  if (tid < 128) {
    int m = tid >> 3, d4 = (tid & 7) * 4;
    float4 v = *(const float4*)(Vf + ((size_t)(b * N_ + mt * 16 + m)) * C_ +
                                hd * HD_ + d4);
    float ci = colinv_s[m];
    float va[4] = {v.x * ci, v.y * ci, v.z * ci, v.w * ci};
    #pragma unroll
    for (int i = 0; i < 4; ++i) {
      unsigned short h = f2bf(va[i]);
      vh_s[d4 + i][m] = h;
      vl_s[d4 + i][m] = f2bf(va[i] - bf2f(h));
    }
  }
  __syncthreads();
  if (tid < 64) {
    int d = tid >> 1, m8 = (tid & 1) * 8;
    uint4 h = *(uint4*)&vh_s[d][m8];
    *(uint4*)(Vth + ((size_t)bh * HD_ + d) * N_ + mt * 16 + m8) = h;
  } else if (tid < 128) {
    int t2 = tid - 64;
    int d = t2 >> 1, m8 = (t2 & 1) * 8;
    uint4 lo = *(uint4*)&vl_s[d][m8];
    *(uint4*)(Vtl + ((size_t)bh * HD_ + d) * N_ + mt * 16 + m8) = lo;
  }
}

// ---------------- pv5: pure GEMM out = E @ V', epilogue *rinv ---------------
__global__ __launch_bounds__(256) void pv5(const unsigned short* __restrict__ E,
                                           const unsigned short* __restrict__ Vth,
                                           const unsigned short* __restrict__ Vtl,
                                           const float* __restrict__ rinv,
                                           unsigned short* __restrict__ aoh,
                                           unsigned short* __restrict__ aol) {
  __shared__ __align__(16) unsigned short vbufh[4096];   // [32d][128m] swz
  __shared__ __align__(16) unsigned short vbufl[4096];
  int tid = threadIdx.x;
  int l = tid & 63, w = tid >> 6;
  int lanelo = l & 15, g16 = l >> 4;
  int flat = blockIdx.y * 8 + blockIdx.x;
  int nf = (flat & 7) * 48 + (flat >> 3);
  int bh = nf >> 3, blk = nf & 7;
  int b = bh / NH_, hd = bh % NH_;
  int q0 = blk * 128 + w * 32;
  size_t bhb = (size_t)bh * (N_ * HD_);
  size_t Eb = (size_t)bh * 64 * 1024 * 16;

  float ri[2][4];
  #pragma unroll
  for (int f = 0; f < 2; ++f)
    #pragma unroll
    for (int t = 0; t < 4; ++t)
      ri[f][t] = rinv[(size_t)bh * N_ + q0 + f * 16 + g16 * 4 + t];

  int vd0 = tid >> 4, vc0 = tid & 15;
  int vd1 = (256 + tid) >> 4;
  const unsigned short* vh0 = Vth + bhb + (size_t)vd0 * N_ + vc0 * 8;
  const unsigned short* vl0 = Vtl + bhb + (size_t)vd0 * N_ + vc0 * 8;
  const unsigned short* vh1 = Vth + bhb + (size_t)vd1 * N_ + vc0 * 8;
  const unsigned short* vl1 = Vtl + bhb + (size_t)vd1 * N_ + vc0 * 8;
  int vp0 = vd0 * 128 + (vc0 ^ (vd0 & 15)) * 8;
  int vp1 = vd1 * 128 + (vc0 ^ (vd1 & 15)) * 8;

  uint4 vrh0 = *(const uint4*)(vh0), vrh1 = *(const uint4*)(vh1);
  uint4 vrl0 = *(const uint4*)(vl0), vrl1 = *(const uint4*)(vl1);

  f32x4 o00 = {0.f,0.f,0.f,0.f}, o01 = {0.f,0.f,0.f,0.f};
  f32x4 o10 = {0.f,0.f,0.f,0.f}, o11 = {0.f,0.f,0.f,0.f};

  for (int ch = 0; ch < 8; ++ch) {
    if (ch) __syncthreads();
    *(uint4*)(vbufh + vp0) = vrh0;
    *(uint4*)(vbufh + vp1) = vrh1;
    *(uint4*)(vbufl + vp0) = vrl0;
    *(uint4*)(vbufl + vp1) = vrl1;
    __syncthreads();
    if (ch < 7) {
      int vko = (ch + 1) * 128;
      vrh0 = *(const uint4*)(vh0 + vko); vrh1 = *(const uint4*)(vh1 + vko);
      vrl0 = *(const uint4*)(vl0 + vko); vrl1 = *(const uint4*)(vl1 + vko);
    }
    #pragma unroll
    for (int pair = 0; pair < 4; ++pair) {
      int kt = ch * 8 + pair * 2 + (g16 >> 1);
      int mi = (g16 & 1) * 8;
      bf16x8 a0 = *(const bf16x8*)(E + Eb + ((size_t)kt * 1024 + q0 + lanelo) * 16 + mi);
      bf16x8 a1 = *(const bf16x8*)(E + Eb + ((size_t)kt * 1024 + q0 + 16 + lanelo) * 16 + mi);
      int vchunk = pair * 4 + g16;
      int d0 = lanelo, d1 = 16 + lanelo;
      bf16x8 v0h = *(const bf16x8*)(vbufh + d0 * 128 + ((vchunk ^ (d0 & 15)) << 3));
      bf16x8 v0l = *(const bf16x8*)(vbufl + d0 * 128 + ((vchunk ^ (d0 & 15)) << 3));
      bf16x8 v1h = *(const bf16x8*)(vbufh + d1 * 128 + ((vchunk ^ (d1 & 15)) << 3));
      bf16x8 v1l = *(const bf16x8*)(vbufl + d1 * 128 + ((vchunk ^ (d1 & 15)) << 3));
      o00 = __builtin_amdgcn_mfma_f32_16x16x32_bf16(a0, v0h, o00, 0, 0, 0);
      o00 = __builtin_amdgcn_mfma_f32_16x16x32_bf16(a0, v0l, o00, 0, 0, 0);
      o01 = __builtin_amdgcn_mfma_f32_16x16x32_bf16(a0, v1h, o01, 0, 0, 0);
      o01 = __builtin_amdgcn_mfma_f32_16x16x32_bf16(a0, v1l, o01, 0, 0, 0);
      o10 = __builtin_amdgcn_mfma_f32_16x16x32_bf16(a1, v0h, o10, 0, 0, 0);
      o10 = __builtin_amdgcn_mfma_f32_16x16x32_bf16(a1, v0l, o10, 0, 0, 0);
      o11 = __builtin_amdgcn_mfma_f32_16x16x32_bf16(a1, v1h, o11, 0, 0, 0);
      o11 = __builtin_amdgcn_mfma_f32_16x16x32_bf16(a1, v1l, o11, 0, 0, 0);
    }
  }
  #pragma unroll
  for (int t = 0; t < 4; ++t) {
    size_t row0 = (size_t)(b * N_ + q0 + g16 * 4 + t) * C_ + hd * HD_;
    size_t row1 = (size_t)(b * N_ + q0 + 16 + g16 * 4 + t) * C_ + hd * HD_;
    float v00 = o00[t] * ri[0][t], v01 = o01[t] * ri[0][t];
    float v10 = o10[t] * ri[1][t], v11 = o11[t] * ri[1][t];
    unsigned short h;
    h = f2bf(v00); aoh[row0 + lanelo]      = h; aol[row0 + lanelo]      = f2bf(v00 - bf2f(h));
    h = f2bf(v01); aoh[row0 + 16 + lanelo] = h; aol[row0 + 16 + lanelo] = f2bf(v01 - bf2f(h));
    h = f2bf(v10); aoh[row1 + lanelo]      = h; aol[row1 + lanelo]      = f2bf(v10 - bf2f(h));
    h = f2bf(v11); aoh[row1 + 16 + lanelo] = h; aol[row1 + 16 + lanelo] = f2bf(v11 - bf2f(h));
  }
}

// ---------------- launch ----------------------------------------------------
extern "C" void kernel_launch(void* const* d_in, const int* in_sizes, int n_in,
                              void* d_out, int out_size, void* d_ws, size_t ws_size,
                              hipStream_t stream) {
  const float* x     = (const float*)d_in[0];
  const float* Wqkv  = (const float*)d_in[1];
  const float* Wproj = (const float*)d_in[2];
  const float* Wgp   = (const float*)d_in[3];
  float* out = (float*)d_out;

  char* base = (char*)d_ws;
  size_t off = 0;
  auto alloc = [&](size_t bytes) {
    void* p = base + off;
    off += (bytes + 255) & ~(size_t)255;
    return p;
  };
  float*  Vf      = (float*)alloc(4096ull * C_ * 4);            // 6.3 MB
  float*  rinv    = (float*)alloc((size_t)BH_ * N_ * 4);
  double* Mgp     = (double*)alloc((size_t)GP_ * C_ * 8);
  int*    group   = (int*)alloc(4096ull * 4);
  unsigned short* xh  = (unsigned short*)alloc(4096ull * C_ * 2);
  unsigned short* xl  = (unsigned short*)alloc(4096ull * C_ * 2);
  unsigned short* Wqh = (unsigned short*)alloc((size_t)H3_ * C_ * 2);
  unsigned short* Wql = (unsigned short*)alloc((size_t)H3_ * C_ * 2);
  unsigned short* Wph = (unsigned short*)alloc((size_t)C_ * C_ * 2);
  unsigned short* Wpl = (unsigned short*)alloc((size_t)C_ * C_ * 2);
  unsigned short* aoh = (unsigned short*)alloc(4096ull * C_ * 2);
  unsigned short* aol = (unsigned short*)alloc(4096ull * C_ * 2);
  const size_t BSZ = (size_t)BH_ * N_ * HD_;
  unsigned short* Qh  = (unsigned short*)alloc(BSZ * 2);
  unsigned short* Ql  = (unsigned short*)alloc(BSZ * 2);
  unsigned short* Kh  = (unsigned short*)alloc(BSZ * 2);
  unsigned short* Kl  = (unsigned short*)alloc(BSZ * 2);
  unsigned short* Vth = (unsigned short*)alloc(BSZ * 2);
  unsigned short* Vtl = (unsigned short*)alloc(BSZ * 2);
  unsigned short* E   = (unsigned short*)alloc((size_t)BH_ * N_ * N_ * 2);  // 96 MB

  conv3<<<dim3(2112), 256, 0, stream>>>(x, Wqkv, Wproj, xh, xl, Wqh, Wql, Wph, Wpl);
  wgp_fuse<<<dim3(30), 256, 0, stream>>>(Wqkv, Wgp, Mgp);
  group_assign2<<<dim3(256), 320, 0, stream>>>(x, Mgp, group);
  gemm_qkv<<<dim3(576), 256, 0, stream>>>(xh, xl, Wqh, Wql,
                                          Qh, Ql, Kh, Kl, Vf);
  score5<<<dim3(16, BH_), 256, 0, stream>>>(Qh, Ql, Kh, Kl, group, rinv, E);
  colv<<<dim3(64, BH_), 256, 0, stream>>>(E, rinv, Vf, Vth, Vtl);
  pv5<<<dim3(8, BH_), 256, 0, stream>>>(E, Vth, Vtl, rinv, aoh, aol);
  gemm_proj<<<dim3(384), 256, 0, stream>>>(aoh, aol, Wph, Wpl, out);
}

// Round 17
// 168.440 us; speedup vs baseline: 1.0113x; 1.0113x over previous
//
#include <hip/hip_runtime.h>
#include <hip/hip_bf16.h>

// HardgroupAttention: B=4, N=1024, C=384, heads=12, hd=32, GP=20.
// conv3 -> wgp_fuse + group argmax (fp64 exact) -> gemm_qkv (128x64 dbuf,
// Q pre-scaled SCALE*log2e) -> score6 (m-SPLIT QK^T sweep: 2 m-halves per
// (bh,qblk), E=keep*exp2 bf16 + PARTIAL rowsums; 1536 blocks) -> colv
// (rinv=1/(p0+p1) inline; colsum -> ci; V'=V*ci bf16 hi/lo transp) ->
// pv5 (pure GEMM E @ V', inline rinv epilogue) -> gemm_proj (64x64 dbuf).

#define B_    4
#define N_    1024
#define C_    384
#define H3_   1152
#define NH_   12
#define HD_   32
#define GP_   20
#define BH_   48
#define QSCALE 0.2550029971791444f   // (hd^-0.5) * log2(e)

typedef __attribute__((ext_vector_type(8))) short bf16x8;
typedef __attribute__((ext_vector_type(4))) float f32x4;
typedef __attribute__((ext_vector_type(4))) unsigned u32x4;

static __device__ __forceinline__ unsigned short f2bf(float x) {
  union { float f; unsigned u; } v; v.f = x;
  unsigned r = v.u + 0x7fff + ((v.u >> 16) & 1);   // RNE
  return (unsigned short)(r >> 16);
}
static __device__ __forceinline__ float bf2f(unsigned short h) {
  union { unsigned u; float f; } v; v.u = ((unsigned)h) << 16;
  return v.f;
}

// ---------------- conv3: split x / Wqkv / Wproj into bf16 hi/lo -------------
__global__ __launch_bounds__(256) void conv3(const float* __restrict__ x,
                                             const float* __restrict__ wq,
                                             const float* __restrict__ wp,
                                             unsigned short* __restrict__ xh,
                                             unsigned short* __restrict__ xl,
                                             unsigned short* __restrict__ wqh,
                                             unsigned short* __restrict__ wql,
                                             unsigned short* __restrict__ wph,
                                             unsigned short* __restrict__ wpl) {
  const int NX = (4096 * C_) / 4, NQ = (H3_ * C_) / 4, NP = (C_ * C_) / 4;
  int idx = blockIdx.x * 256 + threadIdx.x;
  const float* src; unsigned short *dh, *dl; int o;
  if (idx < NX)            { src = x;  dh = xh;  dl = xl;  o = idx; }
  else if (idx < NX + NQ)  { src = wq; dh = wqh; dl = wql; o = idx - NX; }
  else if (idx < NX + NQ + NP) { src = wp; dh = wph; dl = wpl; o = idx - NX - NQ; }
  else return;
  float4 v = *(const float4*)(src + (size_t)o * 4);
  float a[4] = {v.x, v.y, v.z, v.w};
  unsigned short h[4], lo[4];
  #pragma unroll
  for (int i = 0; i < 4; ++i) { h[i] = f2bf(a[i]); lo[i] = f2bf(a[i] - bf2f(h[i])); }
  uint2 ph = {(unsigned)h[0]  | ((unsigned)h[1]  << 16),
              (unsigned)h[2]  | ((unsigned)h[3]  << 16)};
  uint2 pl = {(unsigned)lo[0] | ((unsigned)lo[1] << 16),
              (unsigned)lo[2] | ((unsigned)lo[3] << 16)};
  *(uint2*)(dh + (size_t)o * 4) = ph;
  *(uint2*)(dl + (size_t)o * 4) = pl;
}

// ---------------- M[g][c] = sum_j Wgp[g][j] * Wqkv[j][c]  (fp64) ------------
__global__ __launch_bounds__(256) void wgp_fuse(const float* __restrict__ Wqkv,
                                                const float* __restrict__ Wgp,
                                                double* __restrict__ M) {
  int idx = blockIdx.x * 256 + threadIdx.x;
  if (idx >= GP_ * C_) return;
  int g = idx / C_, c = idx % C_;
  double acc = 0.0;
  for (int j = 0; j < C_; ++j)
    acc += (double)Wgp[g * C_ + j] * (double)Wqkv[(size_t)j * C_ + c];
  M[idx] = acc;
}

// ---------------- group argmax from exact x (fp64, vectorized loads) --------
__global__ __launch_bounds__(320) void group_assign2(const float* __restrict__ x,
                                                     const double* __restrict__ M,
                                                     int* __restrict__ group) {
  __shared__ double sc[16][GP_];
  int tid = threadIdx.x;
  int r = tid / GP_, g = tid % GP_;
  int n = blockIdx.x * 16 + r;
  const float* row = x + (size_t)n * C_;
  const double* w = M + (size_t)g * C_;
  double acc = 0.0;
  #pragma unroll 4
  for (int c = 0; c < C_; c += 4) {
    float4 xv = *(const float4*)(row + c);
    double2 w0 = *(const double2*)(w + c);
    double2 w1 = *(const double2*)(w + c + 2);
    acc += (double)xv.x * w0.x + (double)xv.y * w0.y +
           (double)xv.z * w1.x + (double)xv.w * w1.y;
  }
  sc[r][g] = acc;
  __syncthreads();
  if (g == 0) {
    int best = 0; double bv = sc[r][0];
    #pragma unroll
    for (int j = 1; j < GP_; ++j)
      if (sc[r][j] > bv) { bv = sc[r][j]; best = j; }
    group[n] = best;
  }
}

// ---------------- gemm_qkv: 128x64 tile, dbuf LDS, async-stage split --------
__global__ __launch_bounds__(256) void gemm_qkv(
    const unsigned short* __restrict__ Ah_g, const unsigned short* __restrict__ Al_g,
    const unsigned short* __restrict__ Bh_g, const unsigned short* __restrict__ Bl_g,
    unsigned short* __restrict__ Qh, unsigned short* __restrict__ Ql,
    unsigned short* __restrict__ Kh, unsigned short* __restrict__ Kl,
    float* __restrict__ Vf) {
  __shared__ __align__(16) unsigned short sAh[2][128 * 32];
  __shared__ __align__(16) unsigned short sAl[2][128 * 32];
  __shared__ __align__(16) unsigned short sBh[2][64 * 32];
  __shared__ __align__(16) unsigned short sBl[2][64 * 32];
  int tid = threadIdx.x;
  int l = tid & 63, w = tid >> 6;
  int lanelo = l & 15, g16 = l >> 4;
  int wr = w >> 1, wc = w & 1;
  int flat = blockIdx.x;
  int swz = (flat & 7) * 72 + (flat >> 3);   // 576 = 8*72, bijective
  int bm = swz / 18, bn = swz % 18;

  int ra = tid >> 2, c4 = tid & 3;
  const unsigned short* gAh0 = Ah_g + (size_t)(bm * 128 + ra) * C_ + c4 * 8;
  const unsigned short* gAl0 = Al_g + (size_t)(bm * 128 + ra) * C_ + c4 * 8;
  const unsigned short* gBh0 = Bh_g + (size_t)(bn * 64 + ra) * C_ + c4 * 8;
  const unsigned short* gBl0 = Bl_g + (size_t)(bn * 64 + ra) * C_ + c4 * 8;
  int dsa = ra * 32 + ((c4 ^ (ra & 3)) * 8);

  uint4 r0 = *(const uint4*)(gAh0);
  uint4 r1 = *(const uint4*)(gAh0 + (size_t)64 * C_);
  uint4 r2 = *(const uint4*)(gAl0);
  uint4 r3 = *(const uint4*)(gAl0 + (size_t)64 * C_);
  uint4 r4 = *(const uint4*)(gBh0);
  uint4 r5 = *(const uint4*)(gBl0);

  f32x4 acc[4][2];
  #pragma unroll
  for (int i = 0; i < 4; ++i)
    #pragma unroll
    for (int j = 0; j < 2; ++j) acc[i][j] = (f32x4){0.f, 0.f, 0.f, 0.f};

  int p = 0;
  for (int kk = 0; kk < 12; ++kk) {
    *(uint4*)(&sAh[p][dsa])           = r0;
    *(uint4*)(&sAh[p][dsa + 64 * 32]) = r1;
    *(uint4*)(&sAl[p][dsa])           = r2;
    *(uint4*)(&sAl[p][dsa + 64 * 32]) = r3;
    *(uint4*)(&sBh[p][dsa])           = r4;
    *(uint4*)(&sBl[p][dsa])           = r5;
    __syncthreads();
    if (kk < 11) {
      int ko = (kk + 1) * 32;
      r0 = *(const uint4*)(gAh0 + ko);
      r1 = *(const uint4*)(gAh0 + (size_t)64 * C_ + ko);
      r2 = *(const uint4*)(gAl0 + ko);
      r3 = *(const uint4*)(gAl0 + (size_t)64 * C_ + ko);
      r4 = *(const uint4*)(gBh0 + ko);
      r5 = *(const uint4*)(gBl0 + ko);
    }
    bf16x8 ah[4], al[4], bh8[2], bl8[2];
    #pragma unroll
    for (int i = 0; i < 4; ++i) {
      int row = wr * 64 + i * 16 + lanelo;
      int off = row * 32 + ((g16 ^ (row & 3)) * 8);
      ah[i] = *(const bf16x8*)(&sAh[p][off]);
      al[i] = *(const bf16x8*)(&sAl[p][off]);
    }
    #pragma unroll
    for (int j = 0; j < 2; ++j) {
      int row = wc * 32 + j * 16 + lanelo;
      int off = row * 32 + ((g16 ^ (row & 3)) * 8);
      bh8[j] = *(const bf16x8*)(&sBh[p][off]);
      bl8[j] = *(const bf16x8*)(&sBl[p][off]);
    }
    #pragma unroll
    for (int i = 0; i < 4; ++i)
      #pragma unroll
      for (int j = 0; j < 2; ++j) {
        acc[i][j] = __builtin_amdgcn_mfma_f32_16x16x32_bf16(ah[i], bh8[j], acc[i][j], 0, 0, 0);
        acc[i][j] = __builtin_amdgcn_mfma_f32_16x16x32_bf16(ah[i], bl8[j], acc[i][j], 0, 0, 0);
        acc[i][j] = __builtin_amdgcn_mfma_f32_16x16x32_bf16(al[i], bh8[j], acc[i][j], 0, 0, 0);
      }
    p ^= 1;
  }

  int region = bn / 6;   // 0=Q 1=K 2=V (block-uniform; 6 bn-tiles each)
  #pragma unroll
  for (int i = 0; i < 4; ++i) {
    int mm0 = bm * 128 + wr * 64 + i * 16 + g16 * 4;
    #pragma unroll
    for (int j = 0; j < 2; ++j) {
      int c = bn * 64 + wc * 32 + j * 16 + lanelo;
      int cc = c - region * 384;   // 0..383
      #pragma unroll
      for (int t = 0; t < 4; ++t) {
        int mm = mm0 + t;
        int b = mm >> 10, n = mm & 1023;
        float v = acc[i][j][t];
        if (region == 0) {
          v *= QSCALE;                 // fold log2e: attn uses exp2
          unsigned short h = f2bf(v), lo = f2bf(v - bf2f(h));
          size_t idx = ((size_t)(b * NH_ + (cc >> 5)) * N_ + n) * HD_ + (cc & 31);
          Qh[idx] = h; Ql[idx] = lo;
        } else if (region == 1) {
          unsigned short h = f2bf(v), lo = f2bf(v - bf2f(h));
          size_t idx = ((size_t)(b * NH_ + (cc >> 5)) * N_ + n) * HD_ + (cc & 31);
          Kh[idx] = h; Kl[idx] = lo;
        } else {
          Vf[(size_t)mm * C_ + cc] = v;
        }
      }
    }
  }
}

// ---------------- gemm_proj: 64x64 tile, dbuf LDS, async-stage split --------
__global__ __launch_bounds__(256) void gemm_proj(
    const unsigned short* __restrict__ Ah_g, const unsigned short* __restrict__ Al_g,
    const unsigned short* __restrict__ Bh_g, const unsigned short* __restrict__ Bl_g,
    float* __restrict__ Cm) {
  __shared__ __align__(16) unsigned short sAh[2][64 * 32];
  __shared__ __align__(16) unsigned short sAl[2][64 * 32];
  __shared__ __align__(16) unsigned short sBh[2][64 * 32];
  __shared__ __align__(16) unsigned short sBl[2][64 * 32];
  int tid = threadIdx.x;
  int l = tid & 63, w = tid >> 6;
  int lanelo = l & 15, g16 = l >> 4;
  int wr = w >> 1, wc = w & 1;
  int flat = blockIdx.x;
  int swz = (flat & 7) * 48 + (flat >> 3);   // 384 = 8*48, bijective
  int bm = swz / 6, bn = swz % 6;

  int ra = tid >> 2, c4 = tid & 3;
  const unsigned short* gAh0 = Ah_g + (size_t)(bm * 64 + ra) * C_ + c4 * 8;
  const unsigned short* gAl0 = Al_g + (size_t)(bm * 64 + ra) * C_ + c4 * 8;
  const unsigned short* gBh0 = Bh_g + (size_t)(bn * 64 + ra) * C_ + c4 * 8;
  const unsigned short* gBl0 = Bl_g + (size_t)(bn * 64 + ra) * C_ + c4 * 8;
  int dsa = ra * 32 + ((c4 ^ (ra & 3)) * 8);

  uint4 r0 = *(const uint4*)(gAh0);
  uint4 r1 = *(const uint4*)(gAl0);
  uint4 r2 = *(const uint4*)(gBh0);
  uint4 r3 = *(const uint4*)(gBl0);

  f32x4 acc[2][2];
  #pragma unroll
  for (int i = 0; i < 2; ++i)
    #pragma unroll
    for (int j = 0; j < 2; ++j) acc[i][j] = (f32x4){0.f, 0.f, 0.f, 0.f};

  int p = 0;
  for (int kk = 0; kk < 12; ++kk) {
    *(uint4*)(&sAh[p][dsa]) = r0;
    *(uint4*)(&sAl[p][dsa]) = r1;
    *(uint4*)(&sBh[p][dsa]) = r2;
    *(uint4*)(&sBl[p][dsa]) = r3;
    __syncthreads();
    if (kk < 11) {
      int ko = (kk + 1) * 32;
      r0 = *(const uint4*)(gAh0 + ko);
      r1 = *(const uint4*)(gAl0 + ko);
      r2 = *(const uint4*)(gBh0 + ko);
      r3 = *(const uint4*)(gBl0 + ko);
    }
    bf16x8 ah[2], al[2], bh8[2], bl8[2];
    #pragma unroll
    for (int i = 0; i < 2; ++i) {
      int row = wr * 32 + i * 16 + lanelo;
      int off = row * 32 + ((g16 ^ (row & 3)) * 8);
      ah[i] = *(const bf16x8*)(&sAh[p][off]);
      al[i] = *(const bf16x8*)(&sAl[p][off]);
    }
    #pragma unroll
    for (int j = 0; j < 2; ++j) {
      int row = wc * 32 + j * 16 + lanelo;
      int off = row * 32 + ((g16 ^ (row & 3)) * 8);
      bh8[j] = *(const bf16x8*)(&sBh[p][off]);
      bl8[j] = *(const bf16x8*)(&sBl[p][off]);
    }
    #pragma unroll
    for (int i = 0; i < 2; ++i)
      #pragma unroll
      for (int j = 0; j < 2; ++j) {
        acc[i][j] = __builtin_amdgcn_mfma_f32_16x16x32_bf16(ah[i], bh8[j], acc[i][j], 0, 0, 0);
        acc[i][j] = __builtin_amdgcn_mfma_f32_16x16x32_bf16(ah[i], bl8[j], acc[i][j], 0, 0, 0);
        acc[i][j] = __builtin_amdgcn_mfma_f32_16x16x32_bf16(al[i], bh8[j], acc[i][j], 0, 0, 0);
      }
    p ^= 1;
  }
  #pragma unroll
  for (int i = 0; i < 2; ++i) {
    int mm = bm * 64 + wr * 32 + i * 16 + g16 * 4;
    #pragma unroll
    for (int j = 0; j < 2; ++j) {
      int c = bn * 64 + wc * 32 + j * 16 + lanelo;
      #pragma unroll
      for (int t = 0; t < 4; ++t)
        Cm[(size_t)(mm + t) * C_ + c] = acc[i][j][t];
    }
  }
}

// ---------------- score6: m-SPLIT QK^T sweep -> E + partial rowsums ---------
// grid (32, 48): flat -> (bh, qblk 0..15, mhalf 0..1). 1536 blocks (6/CU).
// Each block sweeps 4 of 8 K-chunks; E for kt in [mh*32, mh*32+32);
// partial rowsum -> rpart[bh][mh][n]. 16B/lane NT stores.
__global__ __launch_bounds__(256) void score6(const unsigned short* __restrict__ Qh,
                                              const unsigned short* __restrict__ Ql,
                                              const unsigned short* __restrict__ Kh,
                                              const unsigned short* __restrict__ Kl,
                                              const int* __restrict__ group,
                                              float* __restrict__ rpart,
                                              unsigned short* __restrict__ E) {
  __shared__ __align__(16) unsigned short kbufh[4096];   // [128kv][32d] swz
  __shared__ __align__(16) unsigned short kbufl[4096];
  __shared__ __align__(16) float bounce[4][512];         // per-wave 2x(16x16), swz
  __shared__ int g_s[1024];
  int tid = threadIdx.x;
  int l = tid & 63, w = tid >> 6;
  int lanelo = l & 15, g16 = l >> 4;
  int flat = blockIdx.y * 32 + blockIdx.x;
  int nf = (flat & 7) * 192 + (flat >> 3);   // 1536 = 8*192, bijective
  int bh = nf >> 5, rest = nf & 31;
  int blk = rest >> 1, mh = rest & 1;
  int b = bh / NH_;
  bool samehead = ((bh % NH_) < NH_ / 2);
  int q0 = blk * 64 + w * 16;
  size_t bhb = (size_t)bh * (N_ * HD_);

  *(int4*)&g_s[tid * 4] = *(const int4*)(group + b * N_ + tid * 4);
  bf16x8 aQh = *(const bf16x8*)(Qh + bhb + (size_t)(q0 + lanelo) * HD_ + g16 * 8);
  bf16x8 aQl = *(const bf16x8*)(Ql + bhb + (size_t)(q0 + lanelo) * HD_ + g16 * 8);
  __syncthreads();
  int gq[4];
  #pragma unroll
  for (int t = 0; t < 4; ++t) gq[t] = g_s[q0 + g16 * 4 + t];

  float s4[4] = {0.f, 0.f, 0.f, 0.f};
  size_t Eb = (size_t)bh * 64 * 1024 * 16;

  // write-phase lane map (constant per thread)
  int wtile = l >> 5;              // 0/1: which kt of the pair
  int wrow  = (l >> 1) & 15;       // q-row within tile
  int whalf = l & 1;               // which 8-col half
  int wb    = wtile * 256 + wrow * 16;
  int wp0   = (((2 * whalf)     ^ (wrow & 3) ^ (wrow >> 2)) << 2);
  int wp1   = (((2 * whalf + 1) ^ (wrow & 3) ^ (wrow >> 2)) << 2);

  for (int ch = mh * 4; ch < mh * 4 + 4; ++ch) {
    __syncthreads();
    #pragma unroll
    for (int t2 = 0; t2 < 2; ++t2) {
      int f2 = t2 * 256 + tid;
      int row = f2 >> 2, c4 = f2 & 3;
      uint4 vh = *(const uint4*)(Kh + bhb + (size_t)(ch * 128 + row) * HD_ + c4 * 8);
      uint4 vl = *(const uint4*)(Kl + bhb + (size_t)(ch * 128 + row) * HD_ + c4 * 8);
      int phys = row * 64 + ((c4 ^ (row & 3)) << 4);
      *(uint4*)((char*)kbufh + phys) = vh;
      *(uint4*)((char*)kbufl + phys) = vl;
    }
    __syncthreads();
    #pragma unroll
    for (int kt2 = 0; kt2 < 8; kt2 += 2) {
      #pragma unroll
      for (int sub = 0; sub < 2; ++sub) {
        int kt2s = kt2 + sub;
        int kt = ch * 8 + kt2s;
        int kvl = kt2s * 16 + lanelo;
        int phys = kvl * 64 + ((g16 ^ (kvl & 3)) << 4);
        bf16x8 bh8 = *(const bf16x8*)((char*)kbufh + phys);
        bf16x8 bl8 = *(const bf16x8*)((char*)kbufl + phys);
        f32x4 acc = {0.f, 0.f, 0.f, 0.f};
        acc = __builtin_amdgcn_mfma_f32_16x16x32_bf16(aQh, bh8, acc, 0, 0, 0);
        acc = __builtin_amdgcn_mfma_f32_16x16x32_bf16(aQh, bl8, acc, 0, 0, 0);
        acc = __builtin_amdgcn_mfma_f32_16x16x32_bf16(aQl, bh8, acc, 0, 0, 0);
        int gcol = g_s[kt * 16 + lanelo];
        #pragma unroll
        for (int t = 0; t < 4; ++t) {
          float e = exp2f(acc[t]);
          s4[t] += e;                               // partial rowsum (this m-half)
          int r = g16 * 4 + t;
          bool keep = ((gcol == gq[t]) == samehead);
          float me = keep ? e : 0.f;
          int pc = (lanelo >> 2) ^ (r & 3) ^ (r >> 2);
          bounce[w][sub * 256 + r * 16 + pc * 4 + (lanelo & 3)] = me;
        }
      }
      // 16B/lane coalesced NT store: lane covers (tile, row, 8 cols)
      float4 f0 = *(float4*)&bounce[w][wb + wp0];
      float4 f1 = *(float4*)&bounce[w][wb + wp1];
      u32x4 st;
      st.x = ((unsigned)f2bf(f0.y) << 16) | f2bf(f0.x);
      st.y = ((unsigned)f2bf(f0.w) << 16) | f2bf(f0.z);
      st.z = ((unsigned)f2bf(f1.y) << 16) | f2bf(f1.x);
      st.w = ((unsigned)f2bf(f1.w) << 16) | f2bf(f1.z);
      int ktw = ch * 8 + kt2 + wtile;
      __builtin_nontemporal_store(st,
          (u32x4*)(E + Eb + ((size_t)ktw * 1024 + q0 + wrow) * 16 + whalf * 8));
    }
  }
  #pragma unroll
  for (int t = 0; t < 4; ++t) {
    #pragma unroll
    for (int off = 1; off < 16; off <<= 1) s4[t] += __shfl_xor(s4[t], off);
  }
  if (lanelo == 0) {
    #pragma unroll
    for (int t = 0; t < 4; ++t)
      rpart[((size_t)bh * 2 + mh) * N_ + q0 + g16 * 4 + t] = s4[t];
  }
}

// ---------------- colv: rinv inline; colsum -> ci; V' = V*ci (transposed) ---
__global__ __launch_bounds__(256) void colv(const unsigned short* __restrict__ E,
                                            const float* __restrict__ rpart,
                                            const float* __restrict__ Vf,
                                            unsigned short* __restrict__ Vth,
                                            unsigned short* __restrict__ Vtl) {
  __shared__ float wsum[4][16];
  __shared__ float colinv_s[16];
  __shared__ unsigned short vh_s[32][16];
  __shared__ unsigned short vl_s[32][16];
  int tid = threadIdx.x;
  int l = tid & 63, w = tid >> 6;
  int flat = blockIdx.y * 64 + blockIdx.x;
  int nf = (flat & 7) * 384 + (flat >> 3);
  int bh = nf >> 6, mt = nf & 63;
  int b = bh / NH_, hd = bh % NH_;
  const unsigned short* Eb = E + ((size_t)(bh * 64 + mt)) * 1024 * 16;
  const float* rp0 = rpart + (size_t)bh * 2 * N_;
  const float* rp1 = rp0 + N_;

  float s[16] = {};
  #pragma unroll
  for (int p = 0; p < 4; ++p) {
    int n = p * 256 + tid;
    uint4 a = *(const uint4*)(Eb + (size_t)n * 16);
    uint4 c = *(const uint4*)(Eb + (size_t)n * 16 + 8);
    float rn = 1.0f / (rp0[n] + rp1[n]);
    unsigned ua[8] = {a.x, a.y, a.z, a.w, c.x, c.y, c.z, c.w};
    #pragma unroll
    for (int i = 0; i < 8; ++i) {
      s[2 * i]     += bf2f((unsigned short)(ua[i] & 0xffff)) * rn;
      s[2 * i + 1] += bf2f((unsigned short)(ua[i] >> 16)) * rn;
    }
  }
  #pragma unroll
  for (int i = 0; i < 16; ++i) {
    #pragma unroll
    for (int off = 1; off < 64; off <<= 1) s[i] += __shfl_xor(s[i], off);
  }
  if (l == 0) {
    #pragma unroll
    for (int i = 0; i < 16; ++i) wsum[w][i] = s[i];
  }
  __syncthreads();
  if (tid < 16)
    colinv_s[tid] = 1.0f / (wsum[0][tid] + wsum[1][tid] + wsum[2][tid] +
                            wsum[3][tid] + 1e-8f);
  __syncthreads();
  if (tid < 128) {
    int m = tid >> 3, d4 = (tid & 7) * 4;
    float4 v = *(const float4*)(Vf + ((size_t)(b * N_ + mt * 16 + m)) * C_ +
                                hd * HD_ + d4);
    float ci = colinv_s[m];
    float va[4] = {v.x * ci, v.y * ci, v.z * ci, v.w * ci};
    #pragma unroll
    for (int i = 0; i < 4; ++i) {
      unsigned short h = f2bf(va[i]);
      vh_s[d4 + i][m] = h;
      vl_s[d4 + i][m] = f2bf(va[i] - bf2f(h));
    }
  }
  __syncthreads();
  if (tid < 64) {
    int d = tid >> 1, m8 = (tid & 1) * 8;
    uint4 h = *(uint4*)&vh_s[d][m8];
    *(uint4*)(Vth + ((size_t)bh * HD_ + d) * N_ + mt * 16 + m8) = h;
  } else if (tid < 128) {
    int t2 = tid - 64;
    int d = t2 >> 1, m8 = (t2 & 1) * 8;
    uint4 lo = *(uint4*)&vl_s[d][m8];
    *(uint4*)(Vtl + ((size_t)bh * HD_ + d) * N_ + mt * 16 + m8) = lo;
  }
}

// ---------------- pv5: pure GEMM out = E @ V', inline-rinv epilogue ---------
__global__ __launch_bounds__(256) void pv5(const unsigned short* __restrict__ E,
                                           const unsigned short* __restrict__ Vth,
                                           const unsigned short* __restrict__ Vtl,
                                           const float* __restrict__ rpart,
                                           unsigned short* __restrict__ aoh,
                                           unsigned short* __restrict__ aol) {
  __shared__ __align__(16) unsigned short vbufh[4096];   // [32d][128m] swz
  __shared__ __align__(16) unsigned short vbufl[4096];
  int tid = threadIdx.x;
  int l = tid & 63, w = tid >> 6;
  int lanelo = l & 15, g16 = l >> 4;
  int flat = blockIdx.y * 8 + blockIdx.x;
  int nf = (flat & 7) * 48 + (flat >> 3);
  int bh = nf >> 3, blk = nf & 7;
  int b = bh / NH_, hd = bh % NH_;
  int q0 = blk * 128 + w * 32;
  size_t bhb = (size_t)bh * (N_ * HD_);
  size_t Eb = (size_t)bh * 64 * 1024 * 16;

  const float* rp0 = rpart + (size_t)bh * 2 * N_;
  const float* rp1 = rp0 + N_;
  float ri[2][4];
  #pragma unroll
  for (int f = 0; f < 2; ++f)
    #pragma unroll
    for (int t = 0; t < 4; ++t) {
      int n = q0 + f * 16 + g16 * 4 + t;
      ri[f][t] = 1.0f / (rp0[n] + rp1[n]);
    }

  int vd0 = tid >> 4, vc0 = tid & 15;
  int vd1 = (256 + tid) >> 4;
  const unsigned short* vh0 = Vth + bhb + (size_t)vd0 * N_ + vc0 * 8;
  const unsigned short* vl0 = Vtl + bhb + (size_t)vd0 * N_ + vc0 * 8;
  const unsigned short* vh1 = Vth + bhb + (size_t)vd1 * N_ + vc0 * 8;
  const unsigned short* vl1 = Vtl + bhb + (size_t)vd1 * N_ + vc0 * 8;
  int vp0 = vd0 * 128 + (vc0 ^ (vd0 & 15)) * 8;
  int vp1 = vd1 * 128 + (vc0 ^ (vd1 & 15)) * 8;

  uint4 vrh0 = *(const uint4*)(vh0), vrh1 = *(const uint4*)(vh1);
  uint4 vrl0 = *(const uint4*)(vl0), vrl1 = *(const uint4*)(vl1);

  f32x4 o00 = {0.f,0.f,0.f,0.f}, o01 = {0.f,0.f,0.f,0.f};
  f32x4 o10 = {0.f,0.f,0.f,0.f}, o11 = {0.f,0.f,0.f,0.f};

  for (int ch = 0; ch < 8; ++ch) {
    if (ch) __syncthreads();
    *(uint4*)(vbufh + vp0) = vrh0;
    *(uint4*)(vbufh + vp1) = vrh1;
    *(uint4*)(vbufl + vp0) = vrl0;
    *(uint4*)(vbufl + vp1) = vrl1;
    __syncthreads();
    if (ch < 7) {
      int vko = (ch + 1) * 128;
      vrh0 = *(const uint4*)(vh0 + vko); vrh1 = *(const uint4*)(vh1 + vko);
      vrl0 = *(const uint4*)(vl0 + vko); vrl1 = *(const uint4*)(vl1 + vko);
    }
    #pragma unroll
    for (int pair = 0; pair < 4; ++pair) {
      int kt = ch * 8 + pair * 2 + (g16 >> 1);
      int mi = (g16 & 1) * 8;
      bf16x8 a0 = *(const bf16x8*)(E + Eb + ((size_t)kt * 1024 + q0 + lanelo) * 16 + mi);
      bf16x8 a1 = *(const bf16x8*)(E + Eb + ((size_t)kt * 1024 + q0 + 16 + lanelo) * 16 + mi);
      int vchunk = pair * 4 + g16;
      int d0 = lanelo, d1 = 16 + lanelo;
      bf16x8 v0h = *(const bf16x8*)(vbufh + d0 * 128 + ((vchunk ^ (d0 & 15)) << 3));
      bf16x8 v0l = *(const bf16x8*)(vbufl + d0 * 128 + ((vchunk ^ (d0 & 15)) << 3));
      bf16x8 v1h = *(const bf16x8*)(vbufh + d1 * 128 + ((vchunk ^ (d1 & 15)) << 3));
      bf16x8 v1l = *(const bf16x8*)(vbufl + d1 * 128 + ((vchunk ^ (d1 & 15)) << 3));
      o00 = __builtin_amdgcn_mfma_f32_16x16x32_bf16(a0, v0h, o00, 0, 0, 0);
      o00 = __builtin_amdgcn_mfma_f32_16x16x32_bf16(a0, v0l, o00, 0, 0, 0);
      o01 = __builtin_amdgcn_mfma_f32_16x16x32_bf16(a0, v1h, o01, 0, 0, 0);
      o01 = __builtin_amdgcn_mfma_f32_16x16x32_bf16(a0, v1l, o01, 0, 0, 0);
      o10 = __builtin_amdgcn_mfma_f32_16x16x32_bf16(a1, v0h, o10, 0, 0, 0);
      o10 = __builtin_amdgcn_mfma_f32_16x16x32_bf16(a1, v0l, o10, 0, 0, 0);
      o11 = __builtin_amdgcn_mfma_f32_16x16x32_bf16(a1, v1h, o11, 0, 0, 0);
      o11 = __builtin_amdgcn_mfma_f32_16x16x32_bf16(a1, v1l, o11, 0, 0, 0);
    }
  }
  #pragma unroll
  for (int t = 0; t < 4; ++t) {
    size_t row0 = (size_t)(b * N_ + q0 + g16 * 4 + t) * C_ + hd * HD_;
    size_t row1 = (size_t)(b * N_ + q0 + 16 + g16 * 4 + t) * C_ + hd * HD_;
    float v00 = o00[t] * ri[0][t], v01 = o01[t] * ri[0][t];
    float v10 = o10[t] * ri[1][t], v11 = o11[t] * ri[1][t];
    unsigned short h;
    h = f2bf(v00); aoh[row0 + lanelo]      = h; aol[row0 + lanelo]      = f2bf(v00 - bf2f(h));
    h = f2bf(v01); aoh[row0 + 16 + lanelo] = h; aol[row0 + 16 + lanelo] = f2bf(v01 - bf2f(h));
    h = f2bf(v10); aoh[row1 + lanelo]      = h; aol[row1 + lanelo]      = f2bf(v10 - bf2f(h));
    h = f2bf(v11); aoh[row1 + 16 + lanelo] = h; aol[row1 + 16 + lanelo] = f2bf(v11 - bf2f(h));
  }
}

// ---------------- launch ----------------------------------------------------
extern "C" void kernel_launch(void* const* d_in, const int* in_sizes, int n_in,
                              void* d_out, int out_size, void* d_ws, size_t ws_size,
                              hipStream_t stream) {
  const float* x     = (const float*)d_in[0];
  const float* Wqkv  = (const float*)d_in[1];
  const float* Wproj = (const float*)d_in[2];
  const float* Wgp   = (const float*)d_in[3];
  float* out = (float*)d_out;

  char* base = (char*)d_ws;
  size_t off = 0;
  auto alloc = [&](size_t bytes) {
    void* p = base + off;
    off += (bytes + 255) & ~(size_t)255;
    return p;
  };
  float*  Vf      = (float*)alloc(4096ull * C_ * 4);            // 6.3 MB
  float*  rpart   = (float*)alloc((size_t)BH_ * 2 * N_ * 4);
  double* Mgp     = (double*)alloc((size_t)GP_ * C_ * 8);
  int*    group   = (int*)alloc(4096ull * 4);
  unsigned short* xh  = (unsigned short*)alloc(4096ull * C_ * 2);
  unsigned short* xl  = (unsigned short*)alloc(4096ull * C_ * 2);
  unsigned short* Wqh = (unsigned short*)alloc((size_t)H3_ * C_ * 2);
  unsigned short* Wql = (unsigned short*)alloc((size_t)H3_ * C_ * 2);
  unsigned short* Wph = (unsigned short*)alloc((size_t)C_ * C_ * 2);
  unsigned short* Wpl = (unsigned short*)alloc((size_t)C_ * C_ * 2);
  unsigned short* aoh = (unsigned short*)alloc(4096ull * C_ * 2);
  unsigned short* aol = (unsigned short*)alloc(4096ull * C_ * 2);
  const size_t BSZ = (size_t)BH_ * N_ * HD_;
  unsigned short* Qh  = (unsigned short*)alloc(BSZ * 2);
  unsigned short* Ql  = (unsigned short*)alloc(BSZ * 2);
  unsigned short* Kh  = (unsigned short*)alloc(BSZ * 2);
  unsigned short* Kl  = (unsigned short*)alloc(BSZ * 2);
  unsigned short* Vth = (unsigned short*)alloc(BSZ * 2);
  unsigned short* Vtl = (unsigned short*)alloc(BSZ * 2);
  unsigned short* E   = (unsigned short*)alloc((size_t)BH_ * N_ * N_ * 2);  // 96 MB

  conv3<<<dim3(2112), 256, 0, stream>>>(x, Wqkv, Wproj, xh, xl, Wqh, Wql, Wph, Wpl);
  wgp_fuse<<<dim3(30), 256, 0, stream>>>(Wqkv, Wgp, Mgp);
  group_assign2<<<dim3(256), 320, 0, stream>>>(x, Mgp, group);
  gemm_qkv<<<dim3(576), 256, 0, stream>>>(xh, xl, Wqh, Wql,
                                          Qh, Ql, Kh, Kl, Vf);
  score6<<<dim3(32, BH_), 256, 0, stream>>>(Qh, Ql, Kh, Kl, group, rpart, E);
  colv<<<dim3(64, BH_), 256, 0, stream>>>(E, rpart, Vf, Vth, Vtl);
  pv5<<<dim3(8, BH_), 256, 0, stream>>>(E, Vth, Vtl, rpart, aoh, aol);
  gemm_proj<<<dim3(384), 256, 0, stream>>>(aoh, aol, Wph, Wpl, out);
}